// Round 14
// baseline (167.234 us; speedup 1.0000x reference)
//
#include <hip/hip_runtime.h>
#include <math.h>

#define GN 8192
#define GF 64
#define GFIN 256
#define NEG 0.2f
#define NFINE 256
#define FCH 32      // ranks per fine chunk
#define NCO 16      // coarse chunks: 16 fine = 512 ranks each

// workspace layout (floats)
#define OFF_WH   0
#define OFF_S1   (GN*GF)
#define OFF_S2   (OFF_S1 + GN)
#define OFF_ZS   (OFF_S2 + GN)
#define OFF_IDX  (OFF_ZS + GN)              // int32: rank -> original row
#define OFF_FA   (OFF_IDX + GN)             // NFINE*GF fine sums, A (atomic)
#define OFF_FB   (OFF_FA + NFINE*GF)        // NFINE*GF fine sums, B (atomic)
#define OFF_FSA  (OFF_FB + NFINE*GF)        // NFINE scalar, A
#define OFF_FSB  (OFF_FSA + NFINE)          // NFINE scalar, B
#define OFF_CA   (OFF_FSB + NFINE)          // NCO*GF coarse sums, A (atomic)
#define OFF_CB   (OFF_CA + NCO*GF)          // NCO*GF coarse sums, B (atomic)
#define OFF_CSA  (OFF_CB + NCO*GF)          // NCO scalar, A
#define OFF_CSB  (OFF_CSA + NCO)            // NCO scalar, B
#define OFF_CKEY (OFF_CSB + NCO)            // NFINE chunk-max keys
#define ZERO_CNT (OFF_CKEY - OFF_FA)        // 35360 contiguous floats to zero

// Kernel 1 (R3/R13-proven): Wh = h @ W, s1 = Wh@a1, s2 = Wh@a2; zero tables.
// W row-major in LDS (b32 broadcast reads, 2-way alias = free); h via
// wave-uniform s_loads; 8 rows/wave, 256 threads.
__global__ __launch_bounds__(256) void k_wh(const float* __restrict__ h,
        const float* __restrict__ W, const float* __restrict__ a,
        float* __restrict__ wsf) {
    float* Wh = wsf + OFF_WH;
    float* s1 = wsf + OFF_S1;
    float* s2 = wsf + OFF_S2;
    __shared__ float Wl[GFIN*GF];            // 64 KB
    int t = threadIdx.x, b = blockIdx.x;
    int lane = t & 63;
    int zm = b*256 + t;                      // 65536 threads cover 35360 slots
    if (zm < ZERO_CNT) wsf[OFF_FA + zm] = 0.f;
    const float4* W4 = (const float4*)W;
    float4* Wl4 = (float4*)Wl;
    #pragma unroll
    for (int m = 0; m < 16; ++m) Wl4[t + m*256] = W4[t + m*256];
    __syncthreads();
    int wid = __builtin_amdgcn_readfirstlane(t >> 6);   // SGPR wave id
    int row0 = b*32 + wid*8;
    const float* hrow = h + (size_t)row0 * GFIN;        // wave-uniform base
    float acc[8] = {0.f,0.f,0.f,0.f,0.f,0.f,0.f,0.f};
    #pragma unroll 8
    for (int k = 0; k < GFIN; ++k) {
        float wv = Wl[k*GF + lane];
        #pragma unroll
        for (int q = 0; q < 8; ++q) acc[q] += hrow[q*GFIN + k] * wv;
    }
    float a1 = a[lane], a2 = a[GF + lane];
    #pragma unroll
    for (int q = 0; q < 8; ++q) {
        int row = row0 + q;
        Wh[(size_t)row*GF + lane] = acc[q];
        float v1 = acc[q]*a1, v2 = acc[q]*a2;
        #pragma unroll
        for (int o = 32; o > 0; o >>= 1) { v1 += __shfl_xor(v1, o); v2 += __shfl_xor(v2, o); }
        if (lane == 0) { s1[row] = v1; s2[row] = v2; }
    }
}

// Kernel 2 (R9-proven rank + two-level scatter): rank-sort s2 (strict order,
// index tiebreak); write zs/idx and the chunk-max key table ckey; atomically
// scatter exp-weighted Wh rows into BOTH fine (rank>>5) and coarse (rank>>9)
// tables. ~2.1M lane atomics (R5/R6 measured 1.05M ~ free).
__global__ __launch_bounds__(512) void k_rank(const float* __restrict__ Whg,
        float* __restrict__ wsf) {
    __shared__ float zl[GN];                 // 32 KB s2 copy
    __shared__ int rl[32];
    __shared__ float redm[8];
    const float* s2 = wsf + OFF_S2;
    float* zs = wsf + OFF_ZS;
    int* idx = (int*)(wsf + OFF_IDX);
    float* fineA = wsf + OFF_FA;
    float* fineB = wsf + OFF_FB;
    float* fSA = wsf + OFF_FSA;
    float* fSB = wsf + OFF_FSB;
    float* coA = wsf + OFF_CA;
    float* coB = wsf + OFF_CB;
    float* cSA = wsf + OFF_CSA;
    float* cSB = wsf + OFF_CSB;
    float* ckey = wsf + OFF_CKEY;
    int t = threadIdx.x, b = blockIdx.x;
    int lane = t & 63, wid = t >> 6;
    const float4* s4 = (const float4*)s2;
    float4* z4 = (float4*)zl;
    float mx = -1e30f;
    for (int m = t; m < GN/4; m += 512) {
        float4 v = s4[m]; z4[m] = v;
        mx = fmaxf(fmaxf(mx, v.x), fmaxf(fmaxf(v.y, v.z), v.w));
    }
    #pragma unroll
    for (int o = 32; o > 0; o >>= 1) mx = fmaxf(mx, __shfl_xor(mx, o));
    if (lane == 0) redm[wid] = mx;
    __syncthreads();
    float Z = redm[0];
    #pragma unroll
    for (int w2 = 1; w2 < 8; ++w2) Z = fmaxf(Z, redm[w2]);
    // rank: 32 j's per block, 16 slices each
    int jl = t >> 4, sl = t & 15;
    int j = b*32 + jl;
    float zj = zl[j];
    int cnt = 0;
    #pragma unroll 4
    for (int i = 0; i < GN/64; ++i) {        // 128 iters x float4
        int m4 = i*16 + sl;
        float4 v = z4[m4];
        int mb = m4*4;
        cnt += (v.x < zj) || (v.x == zj && mb   < j);
        cnt += (v.y < zj) || (v.y == zj && mb+1 < j);
        cnt += (v.z < zj) || (v.z == zj && mb+2 < j);
        cnt += (v.w < zj) || (v.w == zj && mb+3 < j);
    }
    cnt += __shfl_xor(cnt, 1);
    cnt += __shfl_xor(cnt, 2);
    cnt += __shfl_xor(cnt, 4);
    cnt += __shfl_xor(cnt, 8);
    if (sl == 0) {
        zs[cnt] = zj; idx[cnt] = j; rl[jl] = cnt;
        if ((cnt & (FCH-1)) == FCH-1) ckey[cnt >> 5] = zj;   // chunk max
    }
    __syncthreads();
    // two-level atomic scatter: 8 waves x 4 j's = the block's 32 rows
    #pragma unroll
    for (int q = 0; q < 4; ++q) {
        int jj = wid*4 + q;
        int jg = b*32 + jj;
        int r = rl[jj];
        float d = zl[jg] - Z;
        float tA = __expf(d);
        float tB = __expf(NEG*d);
        float w = Whg[(size_t)jg*GF + lane];
        int fc = r >> 5;                     // fine chunk
        int C  = r >> 9;                     // coarse chunk
        atomicAdd(&fineA[fc*GF + lane], tA*w);
        atomicAdd(&fineB[fc*GF + lane], tB*w);
        atomicAdd(&coA[C*GF + lane], tA*w);
        atomicAdd(&coB[C*GF + lane], tB*w);
        if (lane == 0) atomicAdd(&fSA[fc], tA);
        if (lane == 1) atomicAdd(&fSB[fc], tB);
        if (lane == 2) atomicAdd(&cSA[C], tA);
        if (lane == 3) atomicAdd(&cSB[C], tB);
    }
}

// Kernel 3: per-row output, scan-free via two-level tables. One wave per row,
// 2048 blocks. 8-step LDS search on ckey -> fine chunk fc (wave-uniform);
// per side: <=15 coarse + <=15 fine vector point-reads (every chunk lands on
// exactly one side) + exact 32-element value-tested boundary walk.
__global__ __launch_bounds__(256) void k_out(const float* __restrict__ wsf,
        float* __restrict__ out) {
    __shared__ float ck[NFINE];              // 1 KB chunk-max keys
    const float* Wh = wsf + OFF_WH;
    const float* s1 = wsf + OFF_S1;
    const float* zs = wsf + OFF_ZS;
    const int* idx = (const int*)(wsf + OFF_IDX);
    const float* fineA = wsf + OFF_FA;
    const float* fineB = wsf + OFF_FB;
    const float* fSA = wsf + OFF_FSA;
    const float* fSB = wsf + OFF_FSB;
    const float* coA = wsf + OFF_CA;
    const float* coB = wsf + OFF_CB;
    const float* cSA = wsf + OFF_CSA;
    const float* cSB = wsf + OFF_CSB;
    const float* ckey = wsf + OFF_CKEY;
    int t = threadIdx.x;
    int wid = t >> 6, lane = t & 63;
    if (t < NFINE/4) ((float4*)ck)[t] = ((const float4*)ckey)[t];
    __syncthreads();
    int i = blockIdx.x*4 + wid;
    float s1i = s1[i];
    float Z = ck[NFINE-1];                   // = zs[GN-1] = max(s2)
    float g = s1i + Z;
    float m = (g >= 0.f) ? g : NEG*g;        // LeakyReLU(g) = row max of e
    float aA = __expf(g - m);                // <= 1
    float aB = __expf(NEG*g - m);            // <= 1
    float tgt = -s1i;
    int lo = 0, hi = NFINE;                  // first chunk with max-key >= tgt
    #pragma unroll
    for (int it = 0; it < 8; ++it) {
        int mid = (lo + hi) >> 1;
        if (ck[mid] < tgt) lo = mid + 1; else hi = mid;
    }
    int fc = __builtin_amdgcn_readfirstlane(min(lo, NFINE-1));
    int cc = fc >> 4;                        // coarse chunk containing fc
    float va = 0.f, vb = 0.f, sa = 0.f, pb = 0.f;
    for (int C = 0; C < cc; ++C)        { vb += coB[C*GF + lane]; pb += cSB[C]; }
    for (int C = cc+1; C < NCO; ++C)    { va += coA[C*GF + lane]; sa += cSA[C]; }
    for (int f = cc*16; f < fc; ++f)    { vb += fineB[f*GF + lane]; pb += fSB[f]; }
    for (int f = fc+1; f < cc*16+16; ++f){ va += fineA[f*GF + lane]; sa += fSA[f]; }
    #pragma unroll 8
    for (int e = 0; e < FCH; ++e) {          // exact boundary walk (value test)
        int r = fc*FCH + e;
        float zr = zs[r];
        int ir = idx[r];
        float w = Wh[(size_t)ir*GF + lane];
        float d = zr - Z;
        if (zr >= tgt) { float tA = __expf(d);     va += tA*w; sa += tA; }
        else           { float tB = __expf(NEG*d); vb += tB*w; pb += tB; }
    }
    out[(size_t)i*GF + lane] = (aA*va + aB*vb) / (aA*sa + aB*pb);
}

extern "C" void kernel_launch(void* const* d_in, const int* in_sizes, int n_in,
                              void* d_out, int out_size, void* d_ws, size_t ws_size,
                              hipStream_t stream) {
    const float* h = (const float*)d_in[0];
    // d_in[1] = adj (unused by the reference forward)
    const float* W = (const float*)d_in[2];
    const float* a = (const float*)d_in[3];
    float* wsf = (float*)d_ws;
    float* out = (float*)d_out;

    hipLaunchKernelGGL(k_wh,   dim3(GN/32), dim3(256), 0, stream, h, W, a, wsf);
    hipLaunchKernelGGL(k_rank, dim3(GN/32), dim3(512), 0, stream, wsf + OFF_WH, wsf);
    hipLaunchKernelGGL(k_out,  dim3(GN/4),  dim3(256), 0, stream, wsf, out);
}

// Round 15
// 69.612 us; speedup vs baseline: 2.4024x; 2.4024x over previous
//
#include <hip/hip_runtime.h>
#include <math.h>

#define GN 8192
#define GF 64
#define GFIN 256
#define NEG 0.2f
#define NFINE 256
#define FCH 32      // ranks per fine chunk

// workspace layout (floats)
#define OFF_WH   0
#define OFF_S1   (GN*GF)
#define OFF_S2   (OFF_S1 + GN)
#define OFF_ZS   (OFF_S2 + GN)
#define OFF_IDX  (OFF_ZS + GN)              // int32
#define OFF_CHA  (OFF_IDX + GN)             // unused legacy slot spacing
#define OFF_OFA  (OFF_CHA)                  // NFINE*GF exclusive suffix, A
#define OFF_OFB  (OFF_OFA + NFINE*GF)       // NFINE*GF exclusive prefix, B
#define OFF_OSA  (OFF_OFB + NFINE*GF)       // NFINE scalar, A
#define OFF_OSB  (OFF_OSA + NFINE)          // NFINE scalar, B

// Kernel 1: Wh = h @ W, s1 = Wh@a1, s2 = Wh@a2. 512 threads (8 waves/CU),
// 4 rows/wave. h via wave-uniform s_loads; W staged in LDS.
__global__ __launch_bounds__(512) void k_wh(const float* __restrict__ h,
        const float* __restrict__ W, const float* __restrict__ a,
        float* __restrict__ wsf) {
    float* Wh = wsf + OFF_WH;
    float* s1 = wsf + OFF_S1;
    float* s2 = wsf + OFF_S2;
    __shared__ float Wl[GFIN*GF];            // 64 KB
    int t = threadIdx.x, b = blockIdx.x;
    int lane = t & 63;
    const float4* W4 = (const float4*)W;
    float4* Wl4 = (float4*)Wl;
    #pragma unroll
    for (int m = 0; m < 8; ++m) Wl4[t + m*512] = W4[t + m*512];
    __syncthreads();
    int wid = __builtin_amdgcn_readfirstlane(t >> 6);   // SGPR wave id
    int row0 = b*32 + wid*4;
    const float* hrow = h + (size_t)row0 * GFIN;        // wave-uniform base
    float acc[4] = {0.f,0.f,0.f,0.f};
    #pragma unroll 8
    for (int k = 0; k < GFIN; ++k) {
        float wv = Wl[k*GF + lane];
        #pragma unroll
        for (int q = 0; q < 4; ++q) acc[q] += hrow[q*GFIN + k] * wv;
    }
    float a1 = a[lane], a2 = a[GF + lane];
    #pragma unroll
    for (int q = 0; q < 4; ++q) {
        int row = row0 + q;
        Wh[(size_t)row*GF + lane] = acc[q];
        float v1 = acc[q]*a1, v2 = acc[q]*a2;
        #pragma unroll
        for (int o = 32; o > 0; o >>= 1) { v1 += __shfl_xor(v1, o); v2 += __shfl_xor(v2, o); }
        if (lane == 0) { s1[row] = v1; s2[row] = v2; }
    }
}

// Kernel 2: rank-sort s2 (strict total order with index tiebreak).
// 512 threads: 32 j's per block, 16 slices each (8 waves/CU).
__global__ __launch_bounds__(512) void k_rank(float* __restrict__ wsf) {
    __shared__ float zl[GN];                 // 32 KB
    const float* s2 = wsf + OFF_S2;
    float* zs = wsf + OFF_ZS;
    int* idx = (int*)(wsf + OFF_IDX);
    int t = threadIdx.x, b = blockIdx.x;
    const float4* s4 = (const float4*)s2;
    float4* z4 = (float4*)zl;
    for (int m = t; m < GN/4; m += 512) z4[m] = s4[m];
    __syncthreads();
    int jl = t >> 4, sl = t & 15;
    int j = b*32 + jl;
    float zj = zl[j];
    int cnt = 0;
    #pragma unroll 4
    for (int i = 0; i < GN/64; ++i) {        // 128 iters x float4
        int m4 = i*16 + sl;
        float4 v = z4[m4];
        int mb = m4*4;
        cnt += (v.x < zj) || (v.x == zj && mb   < j);
        cnt += (v.y < zj) || (v.y == zj && mb+1 < j);
        cnt += (v.z < zj) || (v.z == zj && mb+2 < j);
        cnt += (v.w < zj) || (v.w == zj && mb+3 < j);
    }
    cnt += __shfl_xor(cnt, 1);
    cnt += __shfl_xor(cnt, 2);
    cnt += __shfl_xor(cnt, 4);
    cnt += __shfl_xor(cnt, 8);
    if (sl == 0) { zs[cnt] = zj; idx[cnt] = j; }
}

// Kernel 3: per-channel fine sums + in-block scans. Block c (0..63) = channel
// c; block 64 = scalar channels. Thread t owns ranks [32t, 32t+32): gathers
// Wh[idx[r]*64+c], sums tA*w / tB*w, then block-wide exclusive prefix (B) and
// TRUE reversed exclusive suffix (A) via shuffle scan + LDS combine.
__global__ __launch_bounds__(256) void k_colscan(float* __restrict__ wsf) {
    __shared__ float stg[NFINE];             // route fA/fB to reversed threads
    __shared__ float wred[4];
    const float* Wh = wsf + OFF_WH;
    const float* zs = wsf + OFF_ZS;
    const int* idx = (const int*)(wsf + OFF_IDX);
    float* ofA = wsf + OFF_OFA;
    float* ofB = wsf + OFF_OFB;
    float* osA = wsf + OFF_OSA;
    float* osB = wsf + OFF_OSB;
    int c = blockIdx.x;
    int t = threadIdx.x, lane = t & 63, wid = t >> 6;
    float Z = zs[GN-1];
    float fA = 0.f, fB = 0.f;
    #pragma unroll 8
    for (int q = 0; q < FCH; ++q) {
        int r = t*FCH + q;
        float d = zs[r] - Z;
        float tA = __expf(d);
        float tB = __expf(NEG*d);
        float w = (c < 64) ? Wh[(size_t)idx[r]*GF + c] : 1.0f;
        fA += tA*w; fB += tB*w;
    }
    // ---- B: exclusive prefix over chunk index t ----
    {
        float ws = fB;
        #pragma unroll
        for (int o = 1; o < 64; o <<= 1) { float y = __shfl_up(ws, o); if (lane >= o) ws += y; }
        if (lane == 63) wred[wid] = ws;
        __syncthreads();
        float blkoff = 0.f;
        #pragma unroll
        for (int w2 = 0; w2 < 4; ++w2) { float x = wred[w2]; if (w2 < wid) blkoff += x; }
        float exB = blkoff + ws - fB;
        if (c < 64) ofB[t*GF + c] = exB; else osB[t] = exB;
    }
    __syncthreads();
    // ---- A: exclusive suffix = reversed exclusive prefix (true scan) ----
    stg[t] = fA;
    __syncthreads();
    {
        int rt = NFINE-1-t;
        float vA = stg[rt];
        float ws = vA;
        #pragma unroll
        for (int o = 1; o < 64; o <<= 1) { float y = __shfl_up(ws, o); if (lane >= o) ws += y; }
        __syncthreads();                     // wred reuse
        if (lane == 63) wred[wid] = ws;
        __syncthreads();
        float blkoff = 0.f;
        #pragma unroll
        for (int w2 = 0; w2 < 4; ++w2) { float x = wred[w2]; if (w2 < wid) blkoff += x; }
        float exA = blkoff + ws - vA;        // sum over chunks > rt
        if (c < 64) ofA[rt*GF + c] = exA; else osA[rt] = exA;
    }
}

// Kernel 4: per-row output. One wave per row, 2048 blocks (32 waves/CU).
// Global binary search + fine-chunk offsets + exact 32-element boundary fix.
__global__ __launch_bounds__(256) void k_out(const float* __restrict__ wsf,
        float* __restrict__ out) {
    const float* Wh = wsf + OFF_WH;
    const float* s1 = wsf + OFF_S1;
    const float* zs = wsf + OFF_ZS;
    const int* idx = (const int*)(wsf + OFF_IDX);
    const float* ofA = wsf + OFF_OFA;
    const float* ofB = wsf + OFF_OFB;
    const float* osA = wsf + OFF_OSA;
    const float* osB = wsf + OFF_OSB;
    int t = threadIdx.x;
    int wid = t >> 6, lane = t & 63;
    int i = blockIdx.x*4 + wid;
    float s1i = s1[i];
    float Z = zs[GN-1];
    float g = s1i + Z;
    float m = (g >= 0.f) ? g : NEG*g;        // LeakyReLU(g) = row max of e
    float aA = __expf(g - m);                // <= 1
    float aB = __expf(NEG*g - m);            // <= 1
    float tgt = -s1i;
    int lo = 0, hi = GN;                     // lower_bound: first zs[k] >= tgt
    #pragma unroll
    for (int it = 0; it < 13; ++it) {
        int mid = (lo + hi) >> 1;
        if (zs[mid] < tgt) lo = mid + 1; else hi = mid;
    }
    int k = lo;
    int fc = __builtin_amdgcn_readfirstlane(min(k >> 5, NFINE-1));
    float va = ofA[fc*GF + lane];            // sum over chunks > fc (A side)
    float vb = ofB[fc*GF + lane];            // sum over chunks < fc (B side)
    float sa = osA[fc], pb = osB[fc];
    #pragma unroll 8
    for (int q = 0; q < FCH; ++q) {
        int r = fc*FCH + q;
        float zr = zs[r];
        int ir = idx[r];
        float w = Wh[(size_t)ir*GF + lane];
        float d = zr - Z;
        if (r >= k) { float tA = __expf(d);     va += tA*w; sa += tA; }
        else        { float tB = __expf(NEG*d); vb += tB*w; pb += tB; }
    }
    out[(size_t)i*GF + lane] = (aA*va + aB*vb) / (aA*sa + aB*pb);
}

extern "C" void kernel_launch(void* const* d_in, const int* in_sizes, int n_in,
                              void* d_out, int out_size, void* d_ws, size_t ws_size,
                              hipStream_t stream) {
    const float* h = (const float*)d_in[0];
    // d_in[1] = adj (unused by the reference forward)
    const float* W = (const float*)d_in[2];
    const float* a = (const float*)d_in[3];
    float* wsf = (float*)d_ws;
    float* out = (float*)d_out;

    hipLaunchKernelGGL(k_wh,      dim3(GN/32), dim3(512), 0, stream, h, W, a, wsf);
    hipLaunchKernelGGL(k_rank,    dim3(GN/32), dim3(512), 0, stream, wsf);
    hipLaunchKernelGGL(k_colscan, dim3(65),    dim3(256), 0, stream, wsf);
    hipLaunchKernelGGL(k_out,     dim3(GN/4),  dim3(256), 0, stream, wsf, out);
}